// Round 10
// baseline (379.544 us; speedup 1.0000x reference)
//
#include <hip/hip_runtime.h>
#include <hip/hip_fp16.h>
#include <math.h>

#define NN 50000
#define FIN 128
#define HH 4
#define CC 64
#define HC (HH*CC)       // 256
#define GG 512
#define EE 800000
#define ET (EE + NN)     // 850000 edges incl. self-loops
#define NEG_SLOPE 0.2f
#define SCAN_NB 196      // ceil(NN/256)

typedef _Float16 half8 __attribute__((ext_vector_type(8)));
typedef _Float16 half4 __attribute__((ext_vector_type(4)));
typedef float floatx4 __attribute__((ext_vector_type(4)));

__device__ __forceinline__ float waveReduceSum(float v) {
    #pragma unroll
    for (int off = 32; off > 0; off >>= 1) v += __shfl_xor(v, off);
    return v;
}

// zero counts / ysum / cnt (accumulated-into buffers; ws is not re-poisoned)
__global__ __launch_bounds__(256) void init0_kernel(int* __restrict__ counts,
                                                    float* __restrict__ ysum) {
    int i = blockIdx.x * 256 + threadIdx.x;
    int stride = gridDim.x * 256;
    for (int j = i; j < NN; j += stride) counts[j] = 0;
    for (int j = i; j < 2 * GG; j += stride) ysum[j] = 0.f;   // ysum then cnt contiguous
}

// histogram of dst + batch count, fused
__global__ __launch_bounds__(256) void histcnt_kernel(const int* __restrict__ ei,
                                                      int* __restrict__ counts,
                                                      const int* __restrict__ batch,
                                                      float* __restrict__ cnt) {
    int e = blockIdx.x * 256 + threadIdx.x;
    if (e < ET) {
        int d = (e < EE) ? ei[EE + e] : e - EE;
        atomicAdd(&counts[d], 1);
    }
    if (e < NN) atomicAdd(&cnt[batch[e]], 1.f);
}

// W1t[n][k] = fp16(W1[k][n]) (256x128) ; W2t[n][k] = fp16(W2[k][n]) (64x256)
__global__ __launch_bounds__(256) void cvtw_kernel(const float* __restrict__ W1,
                                                   const float* __restrict__ W2,
                                                   __half* __restrict__ W1t,
                                                   __half* __restrict__ W2t) {
    int i = blockIdx.x * 256 + threadIdx.x;   // grid exact: 192*256 = 49152
    if (i < HC * FIN) {
        int n = i >> 7, k = i & 127;
        W1t[i] = __float2half(W1[(size_t)k * HC + n]);
    } else {
        int i2 = i - HC * FIN;                // 0..16383
        int n = i2 >> 8, k = i2 & 255;
        W2t[i2] = __float2half(W2[(size_t)k * CC + n]);
    }
}

// ---- three-phase device-wide exclusive scan of counts[NN] ----
__global__ __launch_bounds__(256) void scanA_kernel(const int* __restrict__ counts,
                                                    int* __restrict__ bsum) {
    __shared__ int sh[256];
    int t = threadIdx.x;
    int i = blockIdx.x * 256 + t;
    sh[t] = (i < NN) ? counts[i] : 0;
    __syncthreads();
    #pragma unroll
    for (int off = 128; off > 0; off >>= 1) {
        if (t < off) sh[t] += sh[t + off];
        __syncthreads();
    }
    if (t == 0) bsum[blockIdx.x] = sh[0];
}

__global__ __launch_bounds__(256) void scanB_kernel(int* __restrict__ bsum) {
    __shared__ int sh[256];
    int t = threadIdx.x;
    int v = (t < SCAN_NB) ? bsum[t] : 0;
    sh[t] = v;
    __syncthreads();
    for (int off = 1; off < 256; off <<= 1) {
        int u = (t >= off) ? sh[t - off] : 0;
        __syncthreads();
        sh[t] += u;
        __syncthreads();
    }
    if (t < SCAN_NB) bsum[t] = sh[t] - v;   // exclusive
}

__global__ __launch_bounds__(256) void scanC_kernel(const int* __restrict__ counts,
                                                    const int* __restrict__ bsum,
                                                    int* __restrict__ rowptr,
                                                    int* __restrict__ cursor) {
    __shared__ int sh[256];
    int t = threadIdx.x;
    int i = blockIdx.x * 256 + t;
    int v = (i < NN) ? counts[i] : 0;
    sh[t] = v;
    __syncthreads();
    for (int off = 1; off < 256; off <<= 1) {
        int u = (t >= off) ? sh[t - off] : 0;
        __syncthreads();
        sh[t] += u;
        __syncthreads();
    }
    int excl = sh[t] - v + bsum[blockIdx.x];
    if (i < NN) { rowptr[i] = excl; cursor[i] = excl; }
    if (i == NN - 1) rowptr[NN] = excl + v;   // = ET
}

__global__ __launch_bounds__(256) void fill_kernel(const int* __restrict__ ei,
                                                   int* __restrict__ cursor,
                                                   int* __restrict__ scsr) {
    int e = blockIdx.x * 256 + threadIdx.x;
    if (e >= ET) return;
    int s, d;
    if (e < EE) { s = ei[e]; d = ei[EE + e]; } else { s = d = e - EE; }
    int pos = atomicAdd(&cursor[d], 1);
    scsr[pos] = s;
}

// h1 = x @ W1 via fp16 MFMA (f32 accum); fused a_s1/a_d1.
// A-tile staged in LDS with coalesced float4 loads; +4-float row pad.
__global__ __launch_bounds__(256) void gemm1_mfma_kernel(
    const float* __restrict__ x, const __half* __restrict__ W1t,
    const float* __restrict__ att_src1, const float* __restrict__ att_dst1,
    __half* __restrict__ h1, float* __restrict__ a_s1, float* __restrict__ a_d1)
{
    __shared__ __align__(16) float xs[32][FIN + 4];
    int t = threadIdx.x;
    int n0 = blockIdx.x * 32;
    #pragma unroll
    for (int i = 0; i < 4; ++i) {
        int idx = t + i * 256;             // 0..1023 float4 slots
        int row = idx >> 5, c4 = idx & 31;
        int m = n0 + row; if (m >= NN) m = NN - 1;
        float4 v = *(const float4*)(x + (size_t)m * FIN + c4 * 4);
        *(float4*)&xs[row][c4 * 4] = v;
    }
    __syncthreads();

    int w = t >> 6;                        // wave 0..3
    int l = t & 63;
    int nbase = n0 + (w >> 1) * 16;        // 16-node tile
    int chalf = (w & 1) * 128;             // column half
    int lm = l & 15, lb = l >> 4;
    int lrow = (w >> 1) * 16 + lm;

    half8 afrag[4];
    #pragma unroll
    for (int q = 0; q < 4; ++q) {
        float4 lo = *(const float4*)&xs[lrow][q * 32 + lb * 8];
        float4 hi = *(const float4*)&xs[lrow][q * 32 + lb * 8 + 4];
        half8 f;
        #pragma unroll
        for (int i = 0; i < 4; ++i) {
            f[i] = (_Float16)(&lo.x)[i];
            f[4 + i] = (_Float16)(&hi.x)[i];
        }
        afrag[q] = f;
    }
    floatx4 acc[8];
    #pragma unroll
    for (int tt = 0; tt < 8; ++tt) acc[tt] = (floatx4){0.f, 0.f, 0.f, 0.f};

    const __half* wt = W1t + (size_t)(chalf + lm) * FIN + lb * 8;
    #pragma unroll
    for (int tt = 0; tt < 8; ++tt) {
        const __half* wtt = wt + (size_t)tt * 16 * FIN;
        #pragma unroll
        for (int q = 0; q < 4; ++q) {
            half8 b = *(const half8*)(wtt + q * 32);
            acc[tt] = __builtin_amdgcn_mfma_f32_16x16x32_f16(afrag[q], b, acc[tt], 0, 0, 0);
        }
    }
    #pragma unroll
    for (int hh = 0; hh < 2; ++hh) {
        float as_p[4] = {0.f, 0.f, 0.f, 0.f};
        float ad_p[4] = {0.f, 0.f, 0.f, 0.f};
        #pragma unroll
        for (int tt = 0; tt < 4; ++tt) {
            int ti = hh * 4 + tt;
            int col = chalf + ti * 16 + lm;
            float asw = att_src1[col], adw = att_dst1[col];
            #pragma unroll
            for (int r = 0; r < 4; ++r) {
                int n = nbase + lb * 4 + r;
                float v = acc[ti][r];
                if (n < NN) h1[(size_t)n * HC + col] = __float2half(v);
                as_p[r] += v * asw;
                ad_p[r] += v * adw;
            }
        }
        #pragma unroll
        for (int off = 1; off < 16; off <<= 1) {
            #pragma unroll
            for (int r = 0; r < 4; ++r) {
                as_p[r] += __shfl_xor(as_p[r], off);
                ad_p[r] += __shfl_xor(ad_p[r], off);
            }
        }
        if (lm == 0) {
            int head = (chalf >> 6) + hh;
            #pragma unroll
            for (int r = 0; r < 4; ++r) {
                int n = nbase + lb * 4 + r;
                if (n < NN) { a_s1[n * HH + head] = as_p[r]; a_d1[n * HH + head] = ad_p[r]; }
            }
        }
    }
}

// fused weight + gather layer 1 + bias/relu, fp16 out. 1 wave/dst, 4 dst/block.
__global__ __launch_bounds__(256) void emsg1_kernel(
    const int* __restrict__ rowptr, const int* __restrict__ scsr,
    const float* __restrict__ a_s, const float* __restrict__ a_d,
    const half4* __restrict__ h1v, const float* __restrict__ b1,
    half4* __restrict__ out1v)
{
    int d = blockIdx.x * 4 + (threadIdx.x >> 6);   // grid exact: 12500*4
    int l = threadIdx.x & 63;
    int head = l >> 4;
    int start = rowptr[d], end = rowptr[d + 1];
    float ad = a_d[d * HH + head];
    float den = 0.f;
    float a0 = 0.f, a1 = 0.f, a2 = 0.f, a3 = 0.f;
    int j = start;
    for (; j + 1 < end; j += 2) {
        int s0 = scsr[j], s1 = scsr[j + 1];
        float e0 = a_s[s0 * HH + head] + ad;
        float e1 = a_s[s1 * HH + head] + ad;
        e0 = (e0 > 0.f) ? e0 : NEG_SLOPE * e0;
        e1 = (e1 > 0.f) ? e1 : NEG_SLOPE * e1;
        float w0 = __expf(e0), w1 = __expf(e1);
        half4 v0 = h1v[(size_t)s0 * 64 + l];
        half4 v1 = h1v[(size_t)s1 * 64 + l];
        den += w0 + w1;
        a0 += w0 * (float)v0[0] + w1 * (float)v1[0];
        a1 += w0 * (float)v0[1] + w1 * (float)v1[1];
        a2 += w0 * (float)v0[2] + w1 * (float)v1[2];
        a3 += w0 * (float)v0[3] + w1 * (float)v1[3];
    }
    if (j < end) {
        int s0 = scsr[j];
        float e0 = a_s[s0 * HH + head] + ad;
        e0 = (e0 > 0.f) ? e0 : NEG_SLOPE * e0;
        float w0 = __expf(e0);
        half4 v0 = h1v[(size_t)s0 * 64 + l];
        den += w0;
        a0 += w0 * (float)v0[0];
        a1 += w0 * (float)v0[1];
        a2 += w0 * (float)v0[2];
        a3 += w0 * (float)v0[3];
    }
    float inv = 1.f / (den + 1e-16f);
    float4 bb = *(const float4*)(b1 + l * 4);
    float r0 = a0 * inv + bb.x; r0 = r0 > 0.f ? r0 : 0.f;
    float r1 = a1 * inv + bb.y; r1 = r1 > 0.f ? r1 : 0.f;
    float r2 = a2 * inv + bb.z; r2 = r2 > 0.f ? r2 : 0.f;
    float r3 = a3 * inv + bb.w; r3 = r3 > 0.f ? r3 : 0.f;
    half4 o;
    o[0] = (_Float16)r0; o[1] = (_Float16)r1; o[2] = (_Float16)r2; o[3] = (_Float16)r3;
    out1v[(size_t)d * 64 + l] = o;
}

// h2 = out1r @ W2 via fp16 MFMA; fused a_s2/a_d2. 64 nodes/block, 4 waves.
__global__ __launch_bounds__(256) void gemm2_mfma_kernel(
    const __half* __restrict__ out1r, const __half* __restrict__ W2t,
    const float* __restrict__ att_src2, const float* __restrict__ att_dst2,
    __half* __restrict__ h2, float* __restrict__ a_s2, float* __restrict__ a_d2)
{
    __shared__ __align__(16) __half ys[64][HC + 8];
    int t = threadIdx.x;
    int n0 = blockIdx.x * 64;
    #pragma unroll
    for (int i = 0; i < 8; ++i) {
        int idx = t + i * 256;             // 0..2047 half8 slots
        int row = idx >> 5, c8 = idx & 31;
        int m = n0 + row; if (m >= NN) m = NN - 1;
        *(half8*)&ys[row][c8 * 8] = *(const half8*)(out1r + (size_t)m * HC + c8 * 8);
    }
    __syncthreads();

    int w = t >> 6;
    int l = t & 63;
    int nbase = n0 + w * 16;
    int lm = l & 15, lb = l >> 4;
    int lrow = w * 16 + lm;

    half8 afrag[8];
    #pragma unroll
    for (int q = 0; q < 8; ++q) afrag[q] = *(const half8*)&ys[lrow][q * 32 + lb * 8];

    floatx4 acc[4];
    #pragma unroll
    for (int tt = 0; tt < 4; ++tt) acc[tt] = (floatx4){0.f, 0.f, 0.f, 0.f};

    const __half* wt = W2t + (size_t)lm * HC + lb * 8;
    #pragma unroll
    for (int tt = 0; tt < 4; ++tt) {
        const __half* wtt = wt + (size_t)tt * 16 * HC;
        #pragma unroll
        for (int q = 0; q < 8; ++q) {
            half8 b = *(const half8*)(wtt + q * 32);
            acc[tt] = __builtin_amdgcn_mfma_f32_16x16x32_f16(afrag[q], b, acc[tt], 0, 0, 0);
        }
    }
    float as_p[4] = {0.f, 0.f, 0.f, 0.f};
    float ad_p[4] = {0.f, 0.f, 0.f, 0.f};
    #pragma unroll
    for (int tt = 0; tt < 4; ++tt) {
        int col = tt * 16 + lm;
        float asw = att_src2[col], adw = att_dst2[col];
        #pragma unroll
        for (int r = 0; r < 4; ++r) {
            int n = nbase + lb * 4 + r;
            float v = acc[tt][r];
            if (n < NN) h2[(size_t)n * CC + col] = __float2half(v);
            as_p[r] += v * asw;
            ad_p[r] += v * adw;
        }
    }
    #pragma unroll
    for (int off = 1; off < 16; off <<= 1) {
        #pragma unroll
        for (int r = 0; r < 4; ++r) {
            as_p[r] += __shfl_xor(as_p[r], off);
            ad_p[r] += __shfl_xor(ad_p[r], off);
        }
    }
    if (lm == 0) {
        #pragma unroll
        for (int r = 0; r < 4; ++r) {
            int n = nbase + lb * 4 + r;
            if (n < NN) { a_s2[n] = as_p[r]; a_d2[n] = ad_p[r]; }
        }
    }
}

// fused weight + gather layer 2 + relu/bias + FC-dot + mean-pool.
// 1 wave/dst, 4/block; lane: u = half4 channel (0..15), es = edge slot (0..3).
// Single atomicAdd per dst into ysum[batch[d]] (FC is linear: dot before pool).
__global__ __launch_bounds__(256) void emsg2_kernel(
    const int* __restrict__ rowptr, const int* __restrict__ scsr,
    const float* __restrict__ a_s, const float* __restrict__ a_d,
    const half4* __restrict__ h2v, const float* __restrict__ b2,
    const float* __restrict__ fc_w, const int* __restrict__ batch,
    float* __restrict__ ysum)
{
    int d = blockIdx.x * 4 + (threadIdx.x >> 6);
    int l = threadIdx.x & 63;
    int u = l & 15;
    int es = l >> 4;
    int start = rowptr[d], end = rowptr[d + 1];
    float ad = a_d[d];
    float den = 0.f;
    float a0 = 0.f, a1 = 0.f, a2 = 0.f, a3 = 0.f;
    for (int j = start + es; j < end; j += 4) {
        int s = scsr[j];
        float e = a_s[s] + ad;
        e = (e > 0.f) ? e : NEG_SLOPE * e;
        float w = __expf(e);
        half4 v = h2v[(size_t)s * 16 + u];
        den += w;
        a0 += w * (float)v[0];
        a1 += w * (float)v[1];
        a2 += w * (float)v[2];
        a3 += w * (float)v[3];
    }
    #pragma unroll
    for (int off = 16; off < 64; off <<= 1) {
        den += __shfl_xor(den, off);
        a0 += __shfl_xor(a0, off);
        a1 += __shfl_xor(a1, off);
        a2 += __shfl_xor(a2, off);
        a3 += __shfl_xor(a3, off);
    }
    float inv = 1.f / (den + 1e-16f);
    float4 bb = *(const float4*)(b2 + u * 4);
    float4 fw = *(const float4*)(fc_w + u * 4);
    float h0 = a0 * inv + bb.x; h0 = h0 > 0.f ? h0 : 0.f;
    float h1 = a1 * inv + bb.y; h1 = h1 > 0.f ? h1 : 0.f;
    float h2 = a2 * inv + bb.z; h2 = h2 > 0.f ? h2 : 0.f;
    float h3 = a3 * inv + bb.w; h3 = h3 > 0.f ? h3 : 0.f;
    float part = h0 * fw.x + h1 * fw.y + h2 * fw.z + h3 * fw.w;
    #pragma unroll
    for (int off = 1; off < 16; off <<= 1) part += __shfl_xor(part, off);
    if (l == 0) atomicAdd(&ysum[batch[d]], part);
}

__global__ __launch_bounds__(256) void final_kernel(const float* __restrict__ ysum,
    const float* __restrict__ cnt, const float* __restrict__ fc_b,
    float* __restrict__ out)
{
    int g = blockIdx.x * 256 + threadIdx.x;
    if (g < GG) out[g] = ysum[g] / fmaxf(cnt[g], 1.f) + fc_b[0];
}

extern "C" void kernel_launch(void* const* d_in, const int* in_sizes, int n_in,
                              void* d_out, int out_size, void* d_ws, size_t ws_size,
                              hipStream_t stream)
{
    const float* x        = (const float*)d_in[0];
    const float* W1       = (const float*)d_in[1];
    const float* att_src1 = (const float*)d_in[2];
    const float* att_dst1 = (const float*)d_in[3];
    const float* b1       = (const float*)d_in[4];
    const float* W2       = (const float*)d_in[5];
    const float* att_src2 = (const float*)d_in[6];
    const float* att_dst2 = (const float*)d_in[7];
    const float* b2       = (const float*)d_in[8];
    const float* fc_w     = (const float*)d_in[9];
    const float* fc_b     = (const float*)d_in[10];
    const int*   ei       = (const int*)d_in[11];   // [2, E] -> src = ei, dst = ei + EE
    const int*   batch    = (const int*)d_in[12];
    float* out = (float*)d_out;

    char* p = (char*)d_ws;
    __half* W1t   = (__half*)p; p += (size_t)HC * FIN * sizeof(__half);  // 64 KB
    __half* W2t   = (__half*)p; p += (size_t)CC * HC * sizeof(__half);   // 32 KB
    __half* h1    = (__half*)p; p += (size_t)NN * HC * sizeof(__half);   // 25.6 MB
    __half* out1r = (__half*)p; p += (size_t)NN * HC * sizeof(__half);   // 25.6 MB
    __half* h2    = (__half*)p; p += (size_t)NN * CC * sizeof(__half);   // 6.4 MB
    float* a_s1   = (float*)p;  p += (size_t)NN * HH * sizeof(float);
    float* a_d1   = (float*)p;  p += (size_t)NN * HH * sizeof(float);
    float* a_s2   = (float*)p;  p += NN * sizeof(float);
    float* a_d2   = (float*)p;  p += NN * sizeof(float);
    float* ysum   = (float*)p;  p += GG * sizeof(float);                 // ysum+cnt contiguous
    float* cnt    = (float*)p;  p += GG * sizeof(float);
    int* counts   = (int*)p;    p += NN * sizeof(int);
    int* rowptr   = (int*)p;    p += (NN + 1) * sizeof(int);
    int* cursor   = (int*)p;    p += NN * sizeof(int);
    int* scsr     = (int*)p;    p += ET * sizeof(int);
    int* bsum     = (int*)p;    p += SCAN_NB * sizeof(int);

    const int EB = (ET + 255) / 256;

    init0_kernel<<<256, 256, 0, stream>>>(counts, ysum);
    histcnt_kernel<<<EB, 256, 0, stream>>>(ei, counts, batch, cnt);
    cvtw_kernel<<<(HC * FIN + CC * HC) / 256, 256, 0, stream>>>(W1, W2, W1t, W2t);
    scanA_kernel<<<SCAN_NB, 256, 0, stream>>>(counts, bsum);
    scanB_kernel<<<1, 256, 0, stream>>>(bsum);
    scanC_kernel<<<SCAN_NB, 256, 0, stream>>>(counts, bsum, rowptr, cursor);
    fill_kernel<<<EB, 256, 0, stream>>>(ei, cursor, scsr);
    gemm1_mfma_kernel<<<(NN + 31) / 32, 256, 0, stream>>>(x, W1t, att_src1, att_dst1,
                                                          h1, a_s1, a_d1);
    emsg1_kernel<<<NN / 4, 256, 0, stream>>>(rowptr, scsr, a_s1, a_d1,
                                             (const half4*)h1, b1, (half4*)out1r);
    gemm2_mfma_kernel<<<(NN + 63) / 64, 256, 0, stream>>>(out1r, W2t, att_src2, att_dst2,
                                                          h2, a_s2, a_d2);
    emsg2_kernel<<<NN / 4, 256, 0, stream>>>(rowptr, scsr, a_s2, a_d2,
                                             (const half4*)h2, b2, fc_w, batch, ysum);
    final_kernel<<<(GG + 255) / 256, 256, 0, stream>>>(ysum, cnt, fc_b, out);
}

// Round 11
// 301.294 us; speedup vs baseline: 1.2597x; 1.2597x over previous
//
#include <hip/hip_runtime.h>
#include <hip/hip_fp16.h>
#include <math.h>

#define NN 50000
#define FIN 128
#define HH 4
#define CC 64
#define HC (HH*CC)       // 256
#define GG 512
#define EE 800000
#define ET (EE + NN)     // 850000 edges incl. self-loops
#define NEG_SLOPE 0.2f
#define SCAN_NB 196      // ceil(NN/256)

typedef _Float16 half8 __attribute__((ext_vector_type(8)));
typedef _Float16 half4 __attribute__((ext_vector_type(4)));
typedef float floatx4 __attribute__((ext_vector_type(4)));

__device__ __forceinline__ float waveReduceSum(float v) {
    #pragma unroll
    for (int off = 32; off > 0; off >>= 1) v += __shfl_xor(v, off);
    return v;
}

// zero counts[NN] + gcnt[GG] (contiguous int region)
__global__ __launch_bounds__(256) void init0_kernel(int* __restrict__ counts) {
    int i = blockIdx.x * 256 + threadIdx.x;
    int stride = gridDim.x * 256;
    for (int j = i; j < NN + GG; j += stride) counts[j] = 0;
}

// histogram of dst + group histogram of batch, fused
__global__ __launch_bounds__(256) void histcnt_kernel(const int* __restrict__ ei,
                                                      int* __restrict__ counts,
                                                      const int* __restrict__ batch,
                                                      int* __restrict__ gcnt) {
    int e = blockIdx.x * 256 + threadIdx.x;
    if (e < ET) {
        int d = (e < EE) ? ei[EE + e] : e - EE;
        atomicAdd(&counts[d], 1);
    }
    if (e < NN) atomicAdd(&gcnt[batch[e]], 1);
}

// W1t[n][k] = fp16(W1[k][n]) (256x128) ; W2t[n][k] = fp16(W2[k][n]) (64x256)
__global__ __launch_bounds__(256) void cvtw_kernel(const float* __restrict__ W1,
                                                   const float* __restrict__ W2,
                                                   __half* __restrict__ W1t,
                                                   __half* __restrict__ W2t) {
    int i = blockIdx.x * 256 + threadIdx.x;   // grid exact: 192*256 = 49152
    if (i < HC * FIN) {
        int n = i >> 7, k = i & 127;
        W1t[i] = __float2half(W1[(size_t)k * HC + n]);
    } else {
        int i2 = i - HC * FIN;                // 0..16383
        int n = i2 >> 8, k = i2 & 255;
        W2t[i2] = __float2half(W2[(size_t)k * CC + n]);
    }
}

// ---- three-phase device-wide exclusive scan of counts[NN] ----
__global__ __launch_bounds__(256) void scanA_kernel(const int* __restrict__ counts,
                                                    int* __restrict__ bsum) {
    __shared__ int sh[256];
    int t = threadIdx.x;
    int i = blockIdx.x * 256 + t;
    sh[t] = (i < NN) ? counts[i] : 0;
    __syncthreads();
    #pragma unroll
    for (int off = 128; off > 0; off >>= 1) {
        if (t < off) sh[t] += sh[t + off];
        __syncthreads();
    }
    if (t == 0) bsum[blockIdx.x] = sh[0];
}

__global__ __launch_bounds__(256) void scanB_kernel(int* __restrict__ bsum) {
    __shared__ int sh[256];
    int t = threadIdx.x;
    int v = (t < SCAN_NB) ? bsum[t] : 0;
    sh[t] = v;
    __syncthreads();
    for (int off = 1; off < 256; off <<= 1) {
        int u = (t >= off) ? sh[t - off] : 0;
        __syncthreads();
        sh[t] += u;
        __syncthreads();
    }
    if (t < SCAN_NB) bsum[t] = sh[t] - v;   // exclusive
}

__global__ __launch_bounds__(256) void scanC_kernel(const int* __restrict__ counts,
                                                    const int* __restrict__ bsum,
                                                    int* __restrict__ rowptr,
                                                    int* __restrict__ cursor) {
    __shared__ int sh[256];
    int t = threadIdx.x;
    int i = blockIdx.x * 256 + t;
    int v = (i < NN) ? counts[i] : 0;
    sh[t] = v;
    __syncthreads();
    for (int off = 1; off < 256; off <<= 1) {
        int u = (t >= off) ? sh[t - off] : 0;
        __syncthreads();
        sh[t] += u;
        __syncthreads();
    }
    int excl = sh[t] - v + bsum[blockIdx.x];
    if (i < NN) { rowptr[i] = excl; cursor[i] = excl; }
    if (i == NN - 1) rowptr[NN] = excl + v;   // = ET
}

// exclusive scan of gcnt[GG] -> gptr[GG+1] (single block, GG=512 exact)
__global__ __launch_bounds__(512) void scanG_kernel(const int* __restrict__ gcnt,
                                                    int* __restrict__ gptr) {
    __shared__ int sh[512];
    int t = threadIdx.x;
    int v = gcnt[t];
    sh[t] = v;
    __syncthreads();
    for (int off = 1; off < 512; off <<= 1) {
        int u = (t >= off) ? sh[t - off] : 0;
        __syncthreads();
        sh[t] += u;
        __syncthreads();
    }
    gptr[t] = sh[t] - v;
    if (t == 511) gptr[512] = sh[t];   // = NN
}

__global__ __launch_bounds__(256) void fill_kernel(const int* __restrict__ ei,
                                                   int* __restrict__ cursor,
                                                   int* __restrict__ scsr) {
    int e = blockIdx.x * 256 + threadIdx.x;
    if (e >= ET) return;
    int s, d;
    if (e < EE) { s = ei[e]; d = ei[EE + e]; } else { s = d = e - EE; }
    int pos = atomicAdd(&cursor[d], 1);
    scsr[pos] = s;
}

// h1 = x @ W1 via fp16 MFMA (f32 accum); fused a_s1/a_d1.
// A-tile staged in LDS with coalesced float4 loads; +4-float row pad.
__global__ __launch_bounds__(256) void gemm1_mfma_kernel(
    const float* __restrict__ x, const __half* __restrict__ W1t,
    const float* __restrict__ att_src1, const float* __restrict__ att_dst1,
    __half* __restrict__ h1, float* __restrict__ a_s1, float* __restrict__ a_d1)
{
    __shared__ __align__(16) float xs[32][FIN + 4];
    int t = threadIdx.x;
    int n0 = blockIdx.x * 32;
    #pragma unroll
    for (int i = 0; i < 4; ++i) {
        int idx = t + i * 256;             // 0..1023 float4 slots
        int row = idx >> 5, c4 = idx & 31;
        int m = n0 + row; if (m >= NN) m = NN - 1;
        float4 v = *(const float4*)(x + (size_t)m * FIN + c4 * 4);
        *(float4*)&xs[row][c4 * 4] = v;
    }
    __syncthreads();

    int w = t >> 6;                        // wave 0..3
    int l = t & 63;
    int nbase = n0 + (w >> 1) * 16;        // 16-node tile
    int chalf = (w & 1) * 128;             // column half
    int lm = l & 15, lb = l >> 4;
    int lrow = (w >> 1) * 16 + lm;

    half8 afrag[4];
    #pragma unroll
    for (int q = 0; q < 4; ++q) {
        float4 lo = *(const float4*)&xs[lrow][q * 32 + lb * 8];
        float4 hi = *(const float4*)&xs[lrow][q * 32 + lb * 8 + 4];
        half8 f;
        #pragma unroll
        for (int i = 0; i < 4; ++i) {
            f[i] = (_Float16)(&lo.x)[i];
            f[4 + i] = (_Float16)(&hi.x)[i];
        }
        afrag[q] = f;
    }
    floatx4 acc[8];
    #pragma unroll
    for (int tt = 0; tt < 8; ++tt) acc[tt] = (floatx4){0.f, 0.f, 0.f, 0.f};

    const __half* wt = W1t + (size_t)(chalf + lm) * FIN + lb * 8;
    #pragma unroll
    for (int tt = 0; tt < 8; ++tt) {
        const __half* wtt = wt + (size_t)tt * 16 * FIN;
        #pragma unroll
        for (int q = 0; q < 4; ++q) {
            half8 b = *(const half8*)(wtt + q * 32);
            acc[tt] = __builtin_amdgcn_mfma_f32_16x16x32_f16(afrag[q], b, acc[tt], 0, 0, 0);
        }
    }
    #pragma unroll
    for (int hh = 0; hh < 2; ++hh) {
        float as_p[4] = {0.f, 0.f, 0.f, 0.f};
        float ad_p[4] = {0.f, 0.f, 0.f, 0.f};
        #pragma unroll
        for (int tt = 0; tt < 4; ++tt) {
            int ti = hh * 4 + tt;
            int col = chalf + ti * 16 + lm;
            float asw = att_src1[col], adw = att_dst1[col];
            #pragma unroll
            for (int r = 0; r < 4; ++r) {
                int n = nbase + lb * 4 + r;
                float v = acc[ti][r];
                if (n < NN) h1[(size_t)n * HC + col] = __float2half(v);
                as_p[r] += v * asw;
                ad_p[r] += v * adw;
            }
        }
        #pragma unroll
        for (int off = 1; off < 16; off <<= 1) {
            #pragma unroll
            for (int r = 0; r < 4; ++r) {
                as_p[r] += __shfl_xor(as_p[r], off);
                ad_p[r] += __shfl_xor(ad_p[r], off);
            }
        }
        if (lm == 0) {
            int head = (chalf >> 6) + hh;
            #pragma unroll
            for (int r = 0; r < 4; ++r) {
                int n = nbase + lb * 4 + r;
                if (n < NN) { a_s1[n * HH + head] = as_p[r]; a_d1[n * HH + head] = ad_p[r]; }
            }
        }
    }
}

// fused weight + gather layer 1 + bias/relu, fp16 out. 1 wave/dst, 4 dst/block.
__global__ __launch_bounds__(256) void emsg1_kernel(
    const int* __restrict__ rowptr, const int* __restrict__ scsr,
    const float* __restrict__ a_s, const float* __restrict__ a_d,
    const half4* __restrict__ h1v, const float* __restrict__ b1,
    half4* __restrict__ out1v)
{
    int d = blockIdx.x * 4 + (threadIdx.x >> 6);   // grid exact: 12500*4
    int l = threadIdx.x & 63;
    int head = l >> 4;
    int start = rowptr[d], end = rowptr[d + 1];
    float ad = a_d[d * HH + head];
    float den = 0.f;
    float a0 = 0.f, a1 = 0.f, a2 = 0.f, a3 = 0.f;
    int j = start;
    for (; j + 1 < end; j += 2) {
        int s0 = scsr[j], s1 = scsr[j + 1];
        float e0 = a_s[s0 * HH + head] + ad;
        float e1 = a_s[s1 * HH + head] + ad;
        e0 = (e0 > 0.f) ? e0 : NEG_SLOPE * e0;
        e1 = (e1 > 0.f) ? e1 : NEG_SLOPE * e1;
        float w0 = __expf(e0), w1 = __expf(e1);
        half4 v0 = h1v[(size_t)s0 * 64 + l];
        half4 v1 = h1v[(size_t)s1 * 64 + l];
        den += w0 + w1;
        a0 += w0 * (float)v0[0] + w1 * (float)v1[0];
        a1 += w0 * (float)v0[1] + w1 * (float)v1[1];
        a2 += w0 * (float)v0[2] + w1 * (float)v1[2];
        a3 += w0 * (float)v0[3] + w1 * (float)v1[3];
    }
    if (j < end) {
        int s0 = scsr[j];
        float e0 = a_s[s0 * HH + head] + ad;
        e0 = (e0 > 0.f) ? e0 : NEG_SLOPE * e0;
        float w0 = __expf(e0);
        half4 v0 = h1v[(size_t)s0 * 64 + l];
        den += w0;
        a0 += w0 * (float)v0[0];
        a1 += w0 * (float)v0[1];
        a2 += w0 * (float)v0[2];
        a3 += w0 * (float)v0[3];
    }
    float inv = 1.f / (den + 1e-16f);
    float4 bb = *(const float4*)(b1 + l * 4);
    float r0 = a0 * inv + bb.x; r0 = r0 > 0.f ? r0 : 0.f;
    float r1 = a1 * inv + bb.y; r1 = r1 > 0.f ? r1 : 0.f;
    float r2 = a2 * inv + bb.z; r2 = r2 > 0.f ? r2 : 0.f;
    float r3 = a3 * inv + bb.w; r3 = r3 > 0.f ? r3 : 0.f;
    half4 o;
    o[0] = (_Float16)r0; o[1] = (_Float16)r1; o[2] = (_Float16)r2; o[3] = (_Float16)r3;
    out1v[(size_t)d * 64 + l] = o;
}

// h2 = out1r @ W2 via fp16 MFMA; fused a_s2/a_d2. 64 nodes/block, 4 waves.
__global__ __launch_bounds__(256) void gemm2_mfma_kernel(
    const __half* __restrict__ out1r, const __half* __restrict__ W2t,
    const float* __restrict__ att_src2, const float* __restrict__ att_dst2,
    __half* __restrict__ h2, float* __restrict__ a_s2, float* __restrict__ a_d2)
{
    __shared__ __align__(16) __half ys[64][HC + 8];
    int t = threadIdx.x;
    int n0 = blockIdx.x * 64;
    #pragma unroll
    for (int i = 0; i < 8; ++i) {
        int idx = t + i * 256;             // 0..2047 half8 slots
        int row = idx >> 5, c8 = idx & 31;
        int m = n0 + row; if (m >= NN) m = NN - 1;
        *(half8*)&ys[row][c8 * 8] = *(const half8*)(out1r + (size_t)m * HC + c8 * 8);
    }
    __syncthreads();

    int w = t >> 6;
    int l = t & 63;
    int nbase = n0 + w * 16;
    int lm = l & 15, lb = l >> 4;
    int lrow = w * 16 + lm;

    half8 afrag[8];
    #pragma unroll
    for (int q = 0; q < 8; ++q) afrag[q] = *(const half8*)&ys[lrow][q * 32 + lb * 8];

    floatx4 acc[4];
    #pragma unroll
    for (int tt = 0; tt < 4; ++tt) acc[tt] = (floatx4){0.f, 0.f, 0.f, 0.f};

    const __half* wt = W2t + (size_t)lm * HC + lb * 8;
    #pragma unroll
    for (int tt = 0; tt < 4; ++tt) {
        const __half* wtt = wt + (size_t)tt * 16 * HC;
        #pragma unroll
        for (int q = 0; q < 8; ++q) {
            half8 b = *(const half8*)(wtt + q * 32);
            acc[tt] = __builtin_amdgcn_mfma_f32_16x16x32_f16(afrag[q], b, acc[tt], 0, 0, 0);
        }
    }
    float as_p[4] = {0.f, 0.f, 0.f, 0.f};
    float ad_p[4] = {0.f, 0.f, 0.f, 0.f};
    #pragma unroll
    for (int tt = 0; tt < 4; ++tt) {
        int col = tt * 16 + lm;
        float asw = att_src2[col], adw = att_dst2[col];
        #pragma unroll
        for (int r = 0; r < 4; ++r) {
            int n = nbase + lb * 4 + r;
            float v = acc[tt][r];
            if (n < NN) h2[(size_t)n * CC + col] = __float2half(v);
            as_p[r] += v * asw;
            ad_p[r] += v * adw;
        }
    }
    #pragma unroll
    for (int off = 1; off < 16; off <<= 1) {
        #pragma unroll
        for (int r = 0; r < 4; ++r) {
            as_p[r] += __shfl_xor(as_p[r], off);
            ad_p[r] += __shfl_xor(ad_p[r], off);
        }
    }
    if (lm == 0) {
        #pragma unroll
        for (int r = 0; r < 4; ++r) {
            int n = nbase + lb * 4 + r;
            if (n < NN) { a_s2[n] = as_p[r]; a_d2[n] = ad_p[r]; }
        }
    }
}

// fused weight + gather layer 2 + relu/bias + FC-dot. Writes part[d]; NO atomics.
// 1 wave/dst, 4/block; lane: u = half4 channel (0..15), es = edge slot (0..3).
__global__ __launch_bounds__(256) void emsg2_kernel(
    const int* __restrict__ rowptr, const int* __restrict__ scsr,
    const float* __restrict__ a_s, const float* __restrict__ a_d,
    const half4* __restrict__ h2v, const float* __restrict__ b2,
    const float* __restrict__ fc_w, float* __restrict__ part)
{
    int d = blockIdx.x * 4 + (threadIdx.x >> 6);
    int l = threadIdx.x & 63;
    int u = l & 15;
    int es = l >> 4;
    int start = rowptr[d], end = rowptr[d + 1];
    float ad = a_d[d];
    float den = 0.f;
    float a0 = 0.f, a1 = 0.f, a2 = 0.f, a3 = 0.f;
    for (int j = start + es; j < end; j += 4) {
        int s = scsr[j];
        float e = a_s[s] + ad;
        e = (e > 0.f) ? e : NEG_SLOPE * e;
        float w = __expf(e);
        half4 v = h2v[(size_t)s * 16 + u];
        den += w;
        a0 += w * (float)v[0];
        a1 += w * (float)v[1];
        a2 += w * (float)v[2];
        a3 += w * (float)v[3];
    }
    #pragma unroll
    for (int off = 16; off < 64; off <<= 1) {
        den += __shfl_xor(den, off);
        a0 += __shfl_xor(a0, off);
        a1 += __shfl_xor(a1, off);
        a2 += __shfl_xor(a2, off);
        a3 += __shfl_xor(a3, off);
    }
    float inv = 1.f / (den + 1e-16f);
    float4 bb = *(const float4*)(b2 + u * 4);
    float4 fw = *(const float4*)(fc_w + u * 4);
    float h0 = a0 * inv + bb.x; h0 = h0 > 0.f ? h0 : 0.f;
    float h1 = a1 * inv + bb.y; h1 = h1 > 0.f ? h1 : 0.f;
    float h2 = a2 * inv + bb.z; h2 = h2 > 0.f ? h2 : 0.f;
    float h3 = a3 * inv + bb.w; h3 = h3 > 0.f ? h3 : 0.f;
    float p = h0 * fw.x + h1 * fw.y + h2 * fw.z + h3 * fw.w;
    #pragma unroll
    for (int off = 1; off < 16; off <<= 1) p += __shfl_xor(p, off);
    if (l == 0) part[d] = p;
}

// mean-pool over contiguous group ranges (batch is sorted): 1 wave per group.
__global__ void pool_kernel(const float* __restrict__ part, const int* __restrict__ gptr,
                            const float* __restrict__ fc_b, float* __restrict__ out)
{
    int g = blockIdx.x;
    int lane = threadIdx.x;
    int start = gptr[g], end = gptr[g + 1];
    float s = 0.f;
    for (int i = start + lane; i < end; i += 64) s += part[i];
    s = waveReduceSum(s);
    if (lane == 0) out[g] = s / fmaxf((float)(end - start), 1.f) + fc_b[0];
}

extern "C" void kernel_launch(void* const* d_in, const int* in_sizes, int n_in,
                              void* d_out, int out_size, void* d_ws, size_t ws_size,
                              hipStream_t stream)
{
    const float* x        = (const float*)d_in[0];
    const float* W1       = (const float*)d_in[1];
    const float* att_src1 = (const float*)d_in[2];
    const float* att_dst1 = (const float*)d_in[3];
    const float* b1       = (const float*)d_in[4];
    const float* W2       = (const float*)d_in[5];
    const float* att_src2 = (const float*)d_in[6];
    const float* att_dst2 = (const float*)d_in[7];
    const float* b2       = (const float*)d_in[8];
    const float* fc_w     = (const float*)d_in[9];
    const float* fc_b     = (const float*)d_in[10];
    const int*   ei       = (const int*)d_in[11];   // [2, E] -> src = ei, dst = ei + EE
    const int*   batch    = (const int*)d_in[12];
    float* out = (float*)d_out;

    char* p = (char*)d_ws;
    __half* W1t   = (__half*)p; p += (size_t)HC * FIN * sizeof(__half);  // 64 KB
    __half* W2t   = (__half*)p; p += (size_t)CC * HC * sizeof(__half);   // 32 KB
    __half* h1    = (__half*)p; p += (size_t)NN * HC * sizeof(__half);   // 25.6 MB
    __half* out1r = (__half*)p; p += (size_t)NN * HC * sizeof(__half);   // 25.6 MB
    __half* h2    = (__half*)p; p += (size_t)NN * CC * sizeof(__half);   // 6.4 MB
    float* a_s1   = (float*)p;  p += (size_t)NN * HH * sizeof(float);
    float* a_d1   = (float*)p;  p += (size_t)NN * HH * sizeof(float);
    float* a_s2   = (float*)p;  p += NN * sizeof(float);
    float* a_d2   = (float*)p;  p += NN * sizeof(float);
    float* part   = (float*)p;  p += NN * sizeof(float);
    int* counts   = (int*)p;    p += NN * sizeof(int);                   // counts+gcnt contiguous
    int* gcnt     = (int*)p;    p += GG * sizeof(int);
    int* rowptr   = (int*)p;    p += (NN + 1) * sizeof(int);
    int* cursor   = (int*)p;    p += NN * sizeof(int);
    int* scsr     = (int*)p;    p += ET * sizeof(int);
    int* bsum     = (int*)p;    p += SCAN_NB * sizeof(int);
    int* gptr     = (int*)p;    p += (GG + 1) * sizeof(int);

    const int EB = (ET + 255) / 256;

    init0_kernel<<<256, 256, 0, stream>>>(counts);
    histcnt_kernel<<<EB, 256, 0, stream>>>(ei, counts, batch, gcnt);
    cvtw_kernel<<<(HC * FIN + CC * HC) / 256, 256, 0, stream>>>(W1, W2, W1t, W2t);
    scanA_kernel<<<SCAN_NB, 256, 0, stream>>>(counts, bsum);
    scanB_kernel<<<1, 256, 0, stream>>>(bsum);
    scanC_kernel<<<SCAN_NB, 256, 0, stream>>>(counts, bsum, rowptr, cursor);
    scanG_kernel<<<1, 512, 0, stream>>>(gcnt, gptr);
    fill_kernel<<<EB, 256, 0, stream>>>(ei, cursor, scsr);
    gemm1_mfma_kernel<<<(NN + 31) / 32, 256, 0, stream>>>(x, W1t, att_src1, att_dst1,
                                                          h1, a_s1, a_d1);
    emsg1_kernel<<<NN / 4, 256, 0, stream>>>(rowptr, scsr, a_s1, a_d1,
                                             (const half4*)h1, b1, (half4*)out1r);
    gemm2_mfma_kernel<<<(NN + 63) / 64, 256, 0, stream>>>(out1r, W2t, att_src2, att_dst2,
                                                          h2, a_s2, a_d2);
    emsg2_kernel<<<NN / 4, 256, 0, stream>>>(rowptr, scsr, a_s2, a_d2,
                                             (const half4*)h2, b2, fc_w, part);
    pool_kernel<<<GG, 64, 0, stream>>>(part, gptr, fc_b, out);
}

// Round 12
// 276.821 us; speedup vs baseline: 1.3711x; 1.0884x over previous
//
#include <hip/hip_runtime.h>
#include <hip/hip_fp16.h>
#include <math.h>

#define NN 50000
#define FIN 128
#define HH 4
#define CC 64
#define HC (HH*CC)       // 256
#define GG 512
#define EE 800000
#define ET (EE + NN)     // 850000 edges incl. self-loops
#define NEG_SLOPE 0.2f
#define SCAN_NB 196      // ceil(NN/256)

typedef _Float16 half8 __attribute__((ext_vector_type(8)));
typedef _Float16 half4 __attribute__((ext_vector_type(4)));
typedef float floatx4 __attribute__((ext_vector_type(4)));

__device__ __forceinline__ float waveReduceSum(float v) {
    #pragma unroll
    for (int off = 32; off > 0; off >>= 1) v += __shfl_xor(v, off);
    return v;
}

// zero counts[NN]+gcnt[GG]; also weight fp16 transposes (fused, saves a launch)
__global__ __launch_bounds__(256) void init0_kernel(int* __restrict__ counts,
                                                    const float* __restrict__ W1,
                                                    const float* __restrict__ W2,
                                                    __half* __restrict__ W1t,
                                                    __half* __restrict__ W2t) {
    int i = blockIdx.x * 256 + threadIdx.x;
    int stride = gridDim.x * 256;
    for (int j = i; j < NN + GG; j += stride) counts[j] = 0;
    for (int j = i; j < HC * FIN; j += stride) {
        int n = j >> 7, k = j & 127;
        W1t[j] = __float2half(W1[(size_t)k * HC + n]);
    }
    for (int j = i; j < CC * HC; j += stride) {
        int n = j >> 8, k = j & 255;
        W2t[j] = __float2half(W2[(size_t)k * CC + n]);
    }
}

// histogram of dst + group histogram of batch, fused
__global__ __launch_bounds__(256) void histcnt_kernel(const int* __restrict__ ei,
                                                      int* __restrict__ counts,
                                                      const int* __restrict__ batch,
                                                      int* __restrict__ gcnt) {
    int e = blockIdx.x * 256 + threadIdx.x;
    if (e < ET) {
        int d = (e < EE) ? ei[EE + e] : e - EE;
        atomicAdd(&counts[d], 1);
    }
    if (e < NN) atomicAdd(&gcnt[batch[e]], 1);
}

// ---- device-wide exclusive scan of counts[NN] (A: block reduce) ----
__global__ __launch_bounds__(256) void scanA_kernel(const int* __restrict__ counts,
                                                    int* __restrict__ bsum) {
    __shared__ int sh[256];
    int t = threadIdx.x;
    int i = blockIdx.x * 256 + t;
    sh[t] = (i < NN) ? counts[i] : 0;
    __syncthreads();
    #pragma unroll
    for (int off = 128; off > 0; off >>= 1) {
        if (t < off) sh[t] += sh[t + off];
        __syncthreads();
    }
    if (t == 0) bsum[blockIdx.x] = sh[0];
}

// B: single 512-thread block: scan bsum[SCAN_NB] AND gcnt[GG]->gptr (fused)
__global__ __launch_bounds__(512) void scanB_kernel(int* __restrict__ bsum,
                                                    const int* __restrict__ gcnt,
                                                    int* __restrict__ gptr) {
    __shared__ int sh[512];
    int t = threadIdx.x;
    int v = (t < SCAN_NB) ? bsum[t] : 0;
    sh[t] = v;
    __syncthreads();
    for (int off = 1; off < 512; off <<= 1) {
        int u = (t >= off) ? sh[t - off] : 0;
        __syncthreads();
        sh[t] += u;
        __syncthreads();
    }
    if (t < SCAN_NB) bsum[t] = sh[t] - v;   // exclusive
    __syncthreads();
    int g = gcnt[t];
    sh[t] = g;
    __syncthreads();
    for (int off = 1; off < 512; off <<= 1) {
        int u = (t >= off) ? sh[t - off] : 0;
        __syncthreads();
        sh[t] += u;
        __syncthreads();
    }
    gptr[t] = sh[t] - g;
    if (t == 511) gptr[512] = sh[t];   // = NN
}

__global__ __launch_bounds__(256) void scanC_kernel(const int* __restrict__ counts,
                                                    const int* __restrict__ bsum,
                                                    int* __restrict__ rowptr,
                                                    int* __restrict__ cursor) {
    __shared__ int sh[256];
    int t = threadIdx.x;
    int i = blockIdx.x * 256 + t;
    int v = (i < NN) ? counts[i] : 0;
    sh[t] = v;
    __syncthreads();
    for (int off = 1; off < 256; off <<= 1) {
        int u = (t >= off) ? sh[t - off] : 0;
        __syncthreads();
        sh[t] += u;
        __syncthreads();
    }
    int excl = sh[t] - v + bsum[blockIdx.x];
    if (i < NN) { rowptr[i] = excl; cursor[i] = excl; }
    if (i == NN - 1) rowptr[NN] = excl + v;   // = ET
}

__global__ __launch_bounds__(256) void fill_kernel(const int* __restrict__ ei,
                                                   int* __restrict__ cursor,
                                                   int* __restrict__ scsr) {
    int e = blockIdx.x * 256 + threadIdx.x;
    if (e >= ET) return;
    int s, d;
    if (e < EE) { s = ei[e]; d = ei[EE + e]; } else { s = d = e - EE; }
    int pos = atomicAdd(&cursor[d], 1);
    scsr[pos] = s;
}

// h1 = x @ W1 via fp16 MFMA (f32 accum); fused a_s1/a_d1.
// A-tile staged in LDS with coalesced float4 loads; +4-float row pad.
__global__ __launch_bounds__(256) void gemm1_mfma_kernel(
    const float* __restrict__ x, const __half* __restrict__ W1t,
    const float* __restrict__ att_src1, const float* __restrict__ att_dst1,
    __half* __restrict__ h1, float* __restrict__ a_s1, float* __restrict__ a_d1)
{
    __shared__ __align__(16) float xs[32][FIN + 4];
    int t = threadIdx.x;
    int n0 = blockIdx.x * 32;
    #pragma unroll
    for (int i = 0; i < 4; ++i) {
        int idx = t + i * 256;             // 0..1023 float4 slots
        int row = idx >> 5, c4 = idx & 31;
        int m = n0 + row; if (m >= NN) m = NN - 1;
        float4 v = *(const float4*)(x + (size_t)m * FIN + c4 * 4);
        *(float4*)&xs[row][c4 * 4] = v;
    }
    __syncthreads();

    int w = t >> 6;                        // wave 0..3
    int l = t & 63;
    int nbase = n0 + (w >> 1) * 16;        // 16-node tile
    int chalf = (w & 1) * 128;             // column half
    int lm = l & 15, lb = l >> 4;
    int lrow = (w >> 1) * 16 + lm;

    half8 afrag[4];
    #pragma unroll
    for (int q = 0; q < 4; ++q) {
        float4 lo = *(const float4*)&xs[lrow][q * 32 + lb * 8];
        float4 hi = *(const float4*)&xs[lrow][q * 32 + lb * 8 + 4];
        half8 f;
        #pragma unroll
        for (int i = 0; i < 4; ++i) {
            f[i] = (_Float16)(&lo.x)[i];
            f[4 + i] = (_Float16)(&hi.x)[i];
        }
        afrag[q] = f;
    }
    floatx4 acc[8];
    #pragma unroll
    for (int tt = 0; tt < 8; ++tt) acc[tt] = (floatx4){0.f, 0.f, 0.f, 0.f};

    const __half* wt = W1t + (size_t)(chalf + lm) * FIN + lb * 8;
    #pragma unroll
    for (int tt = 0; tt < 8; ++tt) {
        const __half* wtt = wt + (size_t)tt * 16 * FIN;
        #pragma unroll
        for (int q = 0; q < 4; ++q) {
            half8 b = *(const half8*)(wtt + q * 32);
            acc[tt] = __builtin_amdgcn_mfma_f32_16x16x32_f16(afrag[q], b, acc[tt], 0, 0, 0);
        }
    }
    #pragma unroll
    for (int hh = 0; hh < 2; ++hh) {
        float as_p[4] = {0.f, 0.f, 0.f, 0.f};
        float ad_p[4] = {0.f, 0.f, 0.f, 0.f};
        #pragma unroll
        for (int tt = 0; tt < 4; ++tt) {
            int ti = hh * 4 + tt;
            int col = chalf + ti * 16 + lm;
            float asw = att_src1[col], adw = att_dst1[col];
            #pragma unroll
            for (int r = 0; r < 4; ++r) {
                int n = nbase + lb * 4 + r;
                float v = acc[ti][r];
                if (n < NN) h1[(size_t)n * HC + col] = __float2half(v);
                as_p[r] += v * asw;
                ad_p[r] += v * adw;
            }
        }
        #pragma unroll
        for (int off = 1; off < 16; off <<= 1) {
            #pragma unroll
            for (int r = 0; r < 4; ++r) {
                as_p[r] += __shfl_xor(as_p[r], off);
                ad_p[r] += __shfl_xor(ad_p[r], off);
            }
        }
        if (lm == 0) {
            int head = (chalf >> 6) + hh;
            #pragma unroll
            for (int r = 0; r < 4; ++r) {
                int n = nbase + lb * 4 + r;
                if (n < NN) { a_s1[n * HH + head] = as_p[r]; a_d1[n * HH + head] = ad_p[r]; }
            }
        }
    }
}

// fused weight + gather layer 1 + bias/relu, fp16 out. 1 wave/dst, 4 dst/block.
// x4 unroll: 4 independent gathers in flight per lane (latency hiding).
__global__ __launch_bounds__(256) void emsg1_kernel(
    const int* __restrict__ rowptr, const int* __restrict__ scsr,
    const float* __restrict__ a_s, const float* __restrict__ a_d,
    const half4* __restrict__ h1v, const float* __restrict__ b1,
    half4* __restrict__ out1v)
{
    int d = blockIdx.x * 4 + (threadIdx.x >> 6);   // grid exact: 12500*4
    int l = threadIdx.x & 63;
    int head = l >> 4;
    int start = rowptr[d], end = rowptr[d + 1];
    float ad = a_d[d * HH + head];
    float den = 0.f;
    float a0 = 0.f, a1 = 0.f, a2 = 0.f, a3 = 0.f;
    int j = start;
    for (; j + 3 < end; j += 4) {
        int s0 = scsr[j], s1 = scsr[j + 1], s2 = scsr[j + 2], s3 = scsr[j + 3];
        float e0 = a_s[s0 * HH + head] + ad;
        float e1 = a_s[s1 * HH + head] + ad;
        float e2 = a_s[s2 * HH + head] + ad;
        float e3 = a_s[s3 * HH + head] + ad;
        e0 = (e0 > 0.f) ? e0 : NEG_SLOPE * e0;
        e1 = (e1 > 0.f) ? e1 : NEG_SLOPE * e1;
        e2 = (e2 > 0.f) ? e2 : NEG_SLOPE * e2;
        e3 = (e3 > 0.f) ? e3 : NEG_SLOPE * e3;
        float w0 = __expf(e0), w1 = __expf(e1), w2 = __expf(e2), w3 = __expf(e3);
        half4 v0 = h1v[(size_t)s0 * 64 + l];
        half4 v1 = h1v[(size_t)s1 * 64 + l];
        half4 v2 = h1v[(size_t)s2 * 64 + l];
        half4 v3 = h1v[(size_t)s3 * 64 + l];
        den += (w0 + w1) + (w2 + w3);
        a0 += w0 * (float)v0[0] + w1 * (float)v1[0] + w2 * (float)v2[0] + w3 * (float)v3[0];
        a1 += w0 * (float)v0[1] + w1 * (float)v1[1] + w2 * (float)v2[1] + w3 * (float)v3[1];
        a2 += w0 * (float)v0[2] + w1 * (float)v1[2] + w2 * (float)v2[2] + w3 * (float)v3[2];
        a3 += w0 * (float)v0[3] + w1 * (float)v1[3] + w2 * (float)v2[3] + w3 * (float)v3[3];
    }
    for (; j < end; ++j) {
        int s0 = scsr[j];
        float e0 = a_s[s0 * HH + head] + ad;
        e0 = (e0 > 0.f) ? e0 : NEG_SLOPE * e0;
        float w0 = __expf(e0);
        half4 v0 = h1v[(size_t)s0 * 64 + l];
        den += w0;
        a0 += w0 * (float)v0[0];
        a1 += w0 * (float)v0[1];
        a2 += w0 * (float)v0[2];
        a3 += w0 * (float)v0[3];
    }
    float inv = 1.f / (den + 1e-16f);
    float4 bb = *(const float4*)(b1 + l * 4);
    float r0 = a0 * inv + bb.x; r0 = r0 > 0.f ? r0 : 0.f;
    float r1 = a1 * inv + bb.y; r1 = r1 > 0.f ? r1 : 0.f;
    float r2 = a2 * inv + bb.z; r2 = r2 > 0.f ? r2 : 0.f;
    float r3 = a3 * inv + bb.w; r3 = r3 > 0.f ? r3 : 0.f;
    half4 o;
    o[0] = (_Float16)r0; o[1] = (_Float16)r1; o[2] = (_Float16)r2; o[3] = (_Float16)r3;
    out1v[(size_t)d * 64 + l] = o;
}

// h2 = out1r @ W2 via fp16 MFMA; fused a_s2/a_d2. 64 nodes/block, 4 waves.
__global__ __launch_bounds__(256) void gemm2_mfma_kernel(
    const __half* __restrict__ out1r, const __half* __restrict__ W2t,
    const float* __restrict__ att_src2, const float* __restrict__ att_dst2,
    __half* __restrict__ h2, float* __restrict__ a_s2, float* __restrict__ a_d2)
{
    __shared__ __align__(16) __half ys[64][HC + 8];
    int t = threadIdx.x;
    int n0 = blockIdx.x * 64;
    #pragma unroll
    for (int i = 0; i < 8; ++i) {
        int idx = t + i * 256;             // 0..2047 half8 slots
        int row = idx >> 5, c8 = idx & 31;
        int m = n0 + row; if (m >= NN) m = NN - 1;
        *(half8*)&ys[row][c8 * 8] = *(const half8*)(out1r + (size_t)m * HC + c8 * 8);
    }
    __syncthreads();

    int w = t >> 6;
    int l = t & 63;
    int nbase = n0 + w * 16;
    int lm = l & 15, lb = l >> 4;
    int lrow = w * 16 + lm;

    half8 afrag[8];
    #pragma unroll
    for (int q = 0; q < 8; ++q) afrag[q] = *(const half8*)&ys[lrow][q * 32 + lb * 8];

    floatx4 acc[4];
    #pragma unroll
    for (int tt = 0; tt < 4; ++tt) acc[tt] = (floatx4){0.f, 0.f, 0.f, 0.f};

    const __half* wt = W2t + (size_t)lm * HC + lb * 8;
    #pragma unroll
    for (int tt = 0; tt < 4; ++tt) {
        const __half* wtt = wt + (size_t)tt * 16 * HC;
        #pragma unroll
        for (int q = 0; q < 8; ++q) {
            half8 b = *(const half8*)(wtt + q * 32);
            acc[tt] = __builtin_amdgcn_mfma_f32_16x16x32_f16(afrag[q], b, acc[tt], 0, 0, 0);
        }
    }
    float as_p[4] = {0.f, 0.f, 0.f, 0.f};
    float ad_p[4] = {0.f, 0.f, 0.f, 0.f};
    #pragma unroll
    for (int tt = 0; tt < 4; ++tt) {
        int col = tt * 16 + lm;
        float asw = att_src2[col], adw = att_dst2[col];
        #pragma unroll
        for (int r = 0; r < 4; ++r) {
            int n = nbase + lb * 4 + r;
            float v = acc[tt][r];
            if (n < NN) h2[(size_t)n * CC + col] = __float2half(v);
            as_p[r] += v * asw;
            ad_p[r] += v * adw;
        }
    }
    #pragma unroll
    for (int off = 1; off < 16; off <<= 1) {
        #pragma unroll
        for (int r = 0; r < 4; ++r) {
            as_p[r] += __shfl_xor(as_p[r], off);
            ad_p[r] += __shfl_xor(ad_p[r], off);
        }
    }
    if (lm == 0) {
        #pragma unroll
        for (int r = 0; r < 4; ++r) {
            int n = nbase + lb * 4 + r;
            if (n < NN) { a_s2[n] = as_p[r]; a_d2[n] = ad_p[r]; }
        }
    }
}

// fused weight + gather layer 2 + relu/bias + FC-dot. Writes part[d]; NO atomics.
// 1 wave/dst; lane: u = half4 channel (0..15), es = edge slot (0..3); x2 unroll.
__global__ __launch_bounds__(256) void emsg2_kernel(
    const int* __restrict__ rowptr, const int* __restrict__ scsr,
    const float* __restrict__ a_s, const float* __restrict__ a_d,
    const half4* __restrict__ h2v, const float* __restrict__ b2,
    const float* __restrict__ fc_w, float* __restrict__ part)
{
    int d = blockIdx.x * 4 + (threadIdx.x >> 6);
    int l = threadIdx.x & 63;
    int u = l & 15;
    int es = l >> 4;
    int start = rowptr[d], end = rowptr[d + 1];
    float ad = a_d[d];
    float den = 0.f;
    float a0 = 0.f, a1 = 0.f, a2 = 0.f, a3 = 0.f;
    int j = start + es;
    for (; j + 4 < end; j += 8) {
        int sA = scsr[j], sB = scsr[j + 4];
        float eA = a_s[sA] + ad;
        float eB = a_s[sB] + ad;
        eA = (eA > 0.f) ? eA : NEG_SLOPE * eA;
        eB = (eB > 0.f) ? eB : NEG_SLOPE * eB;
        float wA = __expf(eA), wB = __expf(eB);
        half4 vA = h2v[(size_t)sA * 16 + u];
        half4 vB = h2v[(size_t)sB * 16 + u];
        den += wA + wB;
        a0 += wA * (float)vA[0] + wB * (float)vB[0];
        a1 += wA * (float)vA[1] + wB * (float)vB[1];
        a2 += wA * (float)vA[2] + wB * (float)vB[2];
        a3 += wA * (float)vA[3] + wB * (float)vB[3];
    }
    if (j < end) {
        int s = scsr[j];
        float e = a_s[s] + ad;
        e = (e > 0.f) ? e : NEG_SLOPE * e;
        float w = __expf(e);
        half4 v = h2v[(size_t)s * 16 + u];
        den += w;
        a0 += w * (float)v[0];
        a1 += w * (float)v[1];
        a2 += w * (float)v[2];
        a3 += w * (float)v[3];
    }
    #pragma unroll
    for (int off = 16; off < 64; off <<= 1) {
        den += __shfl_xor(den, off);
        a0 += __shfl_xor(a0, off);
        a1 += __shfl_xor(a1, off);
        a2 += __shfl_xor(a2, off);
        a3 += __shfl_xor(a3, off);
    }
    float inv = 1.f / (den + 1e-16f);
    float4 bb = *(const float4*)(b2 + u * 4);
    float4 fw = *(const float4*)(fc_w + u * 4);
    float h0 = a0 * inv + bb.x; h0 = h0 > 0.f ? h0 : 0.f;
    float h1 = a1 * inv + bb.y; h1 = h1 > 0.f ? h1 : 0.f;
    float h2 = a2 * inv + bb.z; h2 = h2 > 0.f ? h2 : 0.f;
    float h3 = a3 * inv + bb.w; h3 = h3 > 0.f ? h3 : 0.f;
    float p = h0 * fw.x + h1 * fw.y + h2 * fw.z + h3 * fw.w;
    #pragma unroll
    for (int off = 1; off < 16; off <<= 1) p += __shfl_xor(p, off);
    if (l == 0) part[d] = p;
}

// mean-pool over contiguous group ranges (batch is sorted): 1 wave per group.
__global__ void pool_kernel(const float* __restrict__ part, const int* __restrict__ gptr,
                            const float* __restrict__ fc_b, float* __restrict__ out)
{
    int g = blockIdx.x;
    int lane = threadIdx.x;
    int start = gptr[g], end = gptr[g + 1];
    float s = 0.f;
    for (int i = start + lane; i < end; i += 64) s += part[i];
    s = waveReduceSum(s);
    if (lane == 0) out[g] = s / fmaxf((float)(end - start), 1.f) + fc_b[0];
}

extern "C" void kernel_launch(void* const* d_in, const int* in_sizes, int n_in,
                              void* d_out, int out_size, void* d_ws, size_t ws_size,
                              hipStream_t stream)
{
    const float* x        = (const float*)d_in[0];
    const float* W1       = (const float*)d_in[1];
    const float* att_src1 = (const float*)d_in[2];
    const float* att_dst1 = (const float*)d_in[3];
    const float* b1       = (const float*)d_in[4];
    const float* W2       = (const float*)d_in[5];
    const float* att_src2 = (const float*)d_in[6];
    const float* att_dst2 = (const float*)d_in[7];
    const float* b2       = (const float*)d_in[8];
    const float* fc_w     = (const float*)d_in[9];
    const float* fc_b     = (const float*)d_in[10];
    const int*   ei       = (const int*)d_in[11];   // [2, E] -> src = ei, dst = ei + EE
    const int*   batch    = (const int*)d_in[12];
    float* out = (float*)d_out;

    char* p = (char*)d_ws;
    __half* W1t   = (__half*)p; p += (size_t)HC * FIN * sizeof(__half);  // 64 KB
    __half* W2t   = (__half*)p; p += (size_t)CC * HC * sizeof(__half);   // 32 KB
    __half* h1    = (__half*)p; p += (size_t)NN * HC * sizeof(__half);   // 25.6 MB
    __half* out1r = (__half*)p; p += (size_t)NN * HC * sizeof(__half);   // 25.6 MB
    __half* h2    = (__half*)p; p += (size_t)NN * CC * sizeof(__half);   // 6.4 MB
    float* a_s1   = (float*)p;  p += (size_t)NN * HH * sizeof(float);
    float* a_d1   = (float*)p;  p += (size_t)NN * HH * sizeof(float);
    float* a_s2   = (float*)p;  p += NN * sizeof(float);
    float* a_d2   = (float*)p;  p += NN * sizeof(float);
    float* part   = (float*)p;  p += NN * sizeof(float);
    int* counts   = (int*)p;    p += NN * sizeof(int);                   // counts+gcnt contiguous
    int* gcnt     = (int*)p;    p += GG * sizeof(int);
    int* rowptr   = (int*)p;    p += (NN + 1) * sizeof(int);
    int* cursor   = (int*)p;    p += NN * sizeof(int);
    int* scsr     = (int*)p;    p += ET * sizeof(int);
    int* bsum     = (int*)p;    p += SCAN_NB * sizeof(int);
    int* gptr     = (int*)p;    p += (GG + 1) * sizeof(int);

    const int EB = (ET + 255) / 256;

    init0_kernel<<<256, 256, 0, stream>>>(counts, W1, W2, W1t, W2t);
    histcnt_kernel<<<EB, 256, 0, stream>>>(ei, counts, batch, gcnt);
    scanA_kernel<<<SCAN_NB, 256, 0, stream>>>(counts, bsum);
    scanB_kernel<<<1, 512, 0, stream>>>(bsum, gcnt, gptr);
    scanC_kernel<<<SCAN_NB, 256, 0, stream>>>(counts, bsum, rowptr, cursor);
    fill_kernel<<<EB, 256, 0, stream>>>(ei, cursor, scsr);
    gemm1_mfma_kernel<<<(NN + 31) / 32, 256, 0, stream>>>(x, W1t, att_src1, att_dst1,
                                                          h1, a_s1, a_d1);
    emsg1_kernel<<<NN / 4, 256, 0, stream>>>(rowptr, scsr, a_s1, a_d1,
                                             (const half4*)h1, b1, (half4*)out1r);
    gemm2_mfma_kernel<<<(NN + 63) / 64, 256, 0, stream>>>(out1r, W2t, att_src2, att_dst2,
                                                          h2, a_s2, a_d2);
    emsg2_kernel<<<NN / 4, 256, 0, stream>>>(rowptr, scsr, a_s2, a_d2,
                                             (const half4*)h2, b2, fc_w, part);
    pool_kernel<<<GG, 64, 0, stream>>>(part, gptr, fc_b, out);
}